// Round 2
// 571.546 us; speedup vs baseline: 1.0240x; 1.0240x over previous
//
#include <hip/hip_runtime.h>

#define B_   16
#define LD_  1024
#define LQ_  512
#define H_   1024

// Output section offsets (floats)
#define OUT0_F 0ull                  // doc_output  [B, LD, 3H]
#define OUT1_F 50331648ull           // query_output[B, LQ, 2H]
#define OUT2_F 67108864ull           // last        [B, 3H]

// Workspace layout (bytes) — ws is ~1 GiB, no aliasing needed
#define OFF_DH   0ull               // Dh  [B,LD,H] f16  32MB
#define OFF_DL   33554432ull        // Dl  32MB
#define OFF_QH   67108864ull        // Qh  16MB
#define OFF_QL   83886080ull        // Ql  16MB
#define OFF_S    100663296ull       // S fp32 [B,LD,LQ] 32MB
#define OFF_AD   134217728ull       // A_d f16 [B,LD,LQ] 16MB
#define OFF_AQ   150994944ull       // A_q f16 [B,LQ,LD] 16MB
#define OFF_DHT  167772160ull       // DhT [B,H,LD] f16 32MB
#define OFF_QT   201326592ull       // QoutT [B,2H,LQ] f16 32MB
#define OFF_QLEN 235077632ull
#define OFF_RPM  235077888ull       // row partial max [4][B*LD]
#define OFF_RPS  235340032ull
#define OFF_CPM  235602176ull       // col partial max [8][B*LQ]
#define OFF_CPS  235864320ull

typedef _Float16 half8 __attribute__((ext_vector_type(8)));
typedef _Float16 half4v __attribute__((ext_vector_type(4)));
typedef float floatx4 __attribute__((ext_vector_type(4)));

// ---------------------------------------------------------------- async g->lds
__device__ __forceinline__ void gll16(const _Float16* g, _Float16* l) {
#if __has_builtin(__builtin_amdgcn_global_load_lds)
  __builtin_amdgcn_global_load_lds(
      (const __attribute__((address_space(1))) unsigned int*)(unsigned long long)g,
      (__attribute__((address_space(3))) unsigned int*)(unsigned int)(unsigned long long)l,
      16, 0, 0);
#else
  int lane = threadIdx.x & 63;
  *(half8*)(l + lane * 8) = *(const half8*)(g + lane * 8);
#endif
}

__device__ __forceinline__ void omerge(float& m, float& s, float pm, float ps) {
  float nm = fmaxf(m, pm);
  s = s * __expf(m - nm) + ps * __expf(pm - nm);
  m = nm;
}

// -------- cast/split + fp32 passthru copies + fused f16 transposes + qlens blk
__global__ __launch_bounds__(256) void k_cast(
    const float* __restrict__ Dp, const float* __restrict__ Qp,
    const int* __restrict__ dlens,
    const unsigned char* __restrict__ qm, int* __restrict__ qlens,
    _Float16* __restrict__ Dh, _Float16* __restrict__ Dl,
    _Float16* __restrict__ Qh, _Float16* __restrict__ Ql,
    _Float16* __restrict__ DhT, _Float16* __restrict__ QT,
    float* __restrict__ out) {
  int bid = blockIdx.x;
  if (bid == 6144) {
    // ---- q_lens from mask buf (one light block, hidden under the cast grid)
    __shared__ unsigned or_hi, is_f32;
    __shared__ int scnt[B_];
    if (threadIdx.x == 0) { or_hi = 0u; is_f32 = 0u; }
    if (threadIdx.x < B_) scnt[threadIdx.x] = 0;
    __syncthreads();
    const unsigned* w = (const unsigned*)qm;
    unsigned lo = 0u, lf = 0u;
    for (int i = threadIdx.x; i < (B_ * LQ_) / 4; i += 256) {
      unsigned v = w[i];
      lo |= (v >> 8);
      if (v == 0x3F800000u) lf = 1u;
    }
    if (lo) atomicOr(&or_hi, 1u);
    if (lf) atomicOr(&is_f32, 1u);
    __syncthreads();
    int esize4 = (or_hi == 0u) || is_f32;  // i32/f32 storage
    for (int idx = threadIdx.x; idx < B_ * LQ_; idx += 256) {
      int b = idx >> 9;
      int z;
      if (esize4) z = (((const unsigned*)qm)[idx] == 0u);
      else        z = (qm[idx] == 0);
      if (z) atomicAdd(&scnt[b], 1);
    }
    __syncthreads();
    if (threadIdx.x < B_) qlens[threadIdx.x] = scnt[threadIdx.x];
    return;
  }
  __shared__ _Float16 T[64 * 66];
  int t = threadIdx.x;
  int r = t >> 2, cb = (t & 3) << 4;
  bool isD = bid < 4096;
  int b, r0, c0;
  const float* src;
  if (isD) {   // D: [LD,H] 16x16 tiles of 64x64 per batch
    b = bid >> 8; int rest = bid & 255; r0 = (rest >> 4) << 6; c0 = (rest & 15) << 6;
    src = Dp + (size_t)b * LD_ * H_;
  } else {     // Q: [LQ,H] 8x16 tiles per batch
    int t2 = bid - 4096;
    b = t2 >> 7; int rest = t2 & 127; r0 = (rest >> 4) << 6; c0 = (rest & 15) << 6;
    src = Qp + (size_t)b * LQ_ * H_;
  }
  size_t eoff = (size_t)(r0 + r) * H_ + c0 + cb;
  float4 v[4];
#pragma unroll
  for (int k = 0; k < 4; ++k) v[k] = *(const float4*)(src + eoff + (k << 2));
  half4v hi4[4], lo4[4];
#pragma unroll
  for (int k = 0; k < 4; ++k) {
    const float* f = (const float*)&v[k];
#pragma unroll
    for (int e = 0; e < 4; ++e) {
      _Float16 h = (_Float16)f[e];
      hi4[k][e] = h;
      lo4[k][e] = (_Float16)(f[e] - (float)h);
    }
  }
  if (isD) {
    _Float16* dh = Dh + (size_t)b * LD_ * H_ + eoff;
    _Float16* dl = Dl + (size_t)b * LD_ * H_ + eoff;
    float* dob = out + OUT0_F + (size_t)b * LD_ * 3072 + (size_t)(r0 + r) * 3072 + 2048 + c0 + cb;
#pragma unroll
    for (int k = 0; k < 4; ++k) {
      *(half4v*)(dh + (k << 2)) = hi4[k];
      *(half4v*)(dl + (k << 2)) = lo4[k];
      *(float4*)(dob + (k << 2)) = v[k];
    }
    if (r0 + r == dlens[b] - 1) {
      float* o2 = out + OUT2_F + (size_t)b * 3072 + 2048 + c0 + cb;
#pragma unroll
      for (int k = 0; k < 4; ++k) *(float4*)(o2 + (k << 2)) = v[k];
    }
  } else {
    _Float16* qh = Qh + (size_t)b * LQ_ * H_ + eoff;
    _Float16* ql = Ql + (size_t)b * LQ_ * H_ + eoff;
    float* qob = out + OUT1_F + (size_t)b * LQ_ * 2048 + (size_t)(r0 + r) * 2048 + c0 + cb;
#pragma unroll
    for (int k = 0; k < 4; ++k) {
      *(half4v*)(qh + (k << 2)) = hi4[k];
      *(half4v*)(ql + (k << 2)) = lo4[k];
      *(float4*)(qob + (k << 2)) = v[k];
    }
  }
  // LDS transpose of hi
#pragma unroll
  for (int k = 0; k < 4; ++k)
#pragma unroll
    for (int e = 0; e < 4; ++e)
      T[r * 66 + cb + (k << 2) + e] = hi4[k][e];
  __syncthreads();
  int ho = t >> 2, wb = (t & 3) << 4;
  half4v o[4];
#pragma unroll
  for (int k = 0; k < 4; ++k)
#pragma unroll
    for (int e = 0; e < 4; ++e)
      o[k][e] = T[(wb + (k << 2) + e) * 66 + ho];
  half8 h8a, h8b;
#pragma unroll
  for (int e = 0; e < 4; ++e) {
    h8a[e] = o[0][e]; h8a[e + 4] = o[1][e];
    h8b[e] = o[2][e]; h8b[e + 4] = o[3][e];
  }
  if (isD) {
    _Float16* dt = DhT + (size_t)b * H_ * LD_ + (size_t)(c0 + ho) * LD_ + r0 + wb;
    *(half8*)(dt) = h8a;
    *(half8*)(dt + 8) = h8b;
  } else {
    _Float16* qt = QT + (size_t)b * 2048 * LQ_ + (size_t)(c0 + ho) * LQ_ + r0 + wb;
    *(half8*)(qt) = h8a;
    *(half8*)(qt + 8) = h8b;
  }
}

// ---------------- scores: S = Dh Qh^T + cross terms, fused partial softmax stats
__global__ __launch_bounds__(256) void k_gemm_scores(
    const _Float16* __restrict__ Dh, const _Float16* __restrict__ Dl,
    const _Float16* __restrict__ Qh, const _Float16* __restrict__ Ql,
    float* __restrict__ S, const int* __restrict__ qlens, const int* __restrict__ dlens,
    float* __restrict__ rowPM, float* __restrict__ rowPS,
    float* __restrict__ colPM, float* __restrict__ colPS) {
  int raw = blockIdx.x;                       // 512 blocks; XCD-swizzle: batch per XCD
  int xcd = raw & 7, idx = raw >> 3;          // idx 0..63
  int b = xcd + ((idx >> 5) << 3);            // 2 batches per XCD
  int t = idx & 31, tm = t >> 2, tn = t & 3;  // 8 m-tiles, 4 n-tiles
  const int K = H_;
  const _Float16* Ah = Dh + (size_t)b * LD_ * H_;
  const _Float16* Al = Dl + (size_t)b * LD_ * H_;
  const _Float16* Bh = Qh + (size_t)b * LQ_ * H_;
  const _Float16* Bl = Ql + (size_t)b * LQ_ * H_;
  float* Cb = S + (size_t)b * LD_ * LQ_;

  __shared__ _Float16 sAh[128 * 32], sAl[128 * 32], sBh[128 * 32], sBl[128 * 32];
  int lane = threadIdx.x & 63, wave = threadIdx.x >> 6;
  int wm = wave >> 1, wn = wave & 1;
  int m0 = tm << 7, n0 = tn << 7;
  int srow = lane >> 2, scol = (lane & 3) << 3;

  floatx4 acc[4][4];
  floatx4 z = {0.f, 0.f, 0.f, 0.f};
#pragma unroll
  for (int i = 0; i < 4; ++i)
#pragma unroll
    for (int j = 0; j < 4; ++j) acc[i][j] = z;

  for (int k0 = 0; k0 < K; k0 += 32) {
#pragma unroll
    for (int ts = 0; ts < 2; ++ts) {
      int row = (wave << 5) + (ts << 4) + srow;
      int lo = ((wave << 5) + (ts << 4)) << 5;
      size_t ga = (size_t)(m0 + row) * K + k0 + scol;
      size_t gb = (size_t)(n0 + row) * K + k0 + scol;
      gll16(Ah + ga, sAh + lo);
      gll16(Al + ga, sAl + lo);
      gll16(Bh + gb, sBh + lo);
      gll16(Bl + gb, sBl + lo);
    }
    __syncthreads();
    int lk = (lane >> 4) << 3, lr = lane & 15;
    half8 ah[4], al4[4], bh[4], bl4[4];
#pragma unroll
    for (int i = 0; i < 4; ++i) {
      int ar = ((wm << 6) + (i << 4) + lr) << 5;
      int br = ((wn << 6) + (i << 4) + lr) << 5;
      ah[i]  = *(const half8*)(sAh + ar + lk);
      al4[i] = *(const half8*)(sAl + ar + lk);
      bh[i]  = *(const half8*)(sBh + br + lk);
      bl4[i] = *(const half8*)(sBl + br + lk);
    }
#pragma unroll
    for (int i = 0; i < 4; ++i)
#pragma unroll
      for (int j = 0; j < 4; ++j) {
        acc[i][j] = __builtin_amdgcn_mfma_f32_16x16x32_f16(ah[i],  bh[j],  acc[i][j], 0, 0, 0);
        acc[i][j] = __builtin_amdgcn_mfma_f32_16x16x32_f16(ah[i],  bl4[j], acc[i][j], 0, 0, 0);
        acc[i][j] = __builtin_amdgcn_mfma_f32_16x16x32_f16(al4[i], bh[j],  acc[i][j], 0, 0, 0);
      }
    __syncthreads();
  }
  int quad = lane >> 4, l15 = lane & 15;
  // store S
#pragma unroll
  for (int i = 0; i < 4; ++i) {
    int mb = m0 + (wm << 6) + (i << 4) + (quad << 2);
#pragma unroll
    for (int j = 0; j < 4; ++j) {
      int n = n0 + (wn << 6) + (j << 4) + l15;
#pragma unroll
      for (int rr = 0; rr < 4; ++rr)
        Cb[(size_t)(mb + rr) * LQ_ + n] = acc[i][j][rr];
    }
  }
  // ---- fused partial softmax stats (reuse LDS) ----
  int qlen = qlens[b], dlen = dlens[b];
  float* redM = (float*)sAh;  // [128][2]
  float* redS = (float*)sAl;
  float* cdM  = (float*)sBh;  // [128][2]
  float* cdS  = (float*)sBl;
  // row partials: per row, over this block's 128 cols (q < qlen mask)
#pragma unroll
  for (int i = 0; i < 4; ++i) {
#pragma unroll
    for (int rr = 0; rr < 4; ++rr) {
      float mx = -1e30f;
#pragma unroll
      for (int j = 0; j < 4; ++j) {
        int q = n0 + (wn << 6) + (j << 4) + l15;
        if (q < qlen) mx = fmaxf(mx, acc[i][j][rr]);
      }
      float s = 0.f;
#pragma unroll
      for (int j = 0; j < 4; ++j) {
        int q = n0 + (wn << 6) + (j << 4) + l15;
        if (q < qlen) s += __expf(acc[i][j][rr] - mx);
      }
#pragma unroll
      for (int off = 1; off < 16; off <<= 1) {
        float om = __shfl_xor(mx, off);
        float os = __shfl_xor(s, off);
        omerge(mx, s, om, os);
      }
      if (l15 == 0) {
        int rl = (wm << 6) + (i << 4) + (quad << 2) + rr;
        redM[(rl << 1) + wn] = mx;
        redS[(rl << 1) + wn] = s;
      }
    }
  }
  // col partials: per col, over this block's 128 rows (d < dlen mask)
#pragma unroll
  for (int j = 0; j < 4; ++j) {
    float mx = -1e30f;
#pragma unroll
    for (int i = 0; i < 4; ++i)
#pragma unroll
      for (int rr = 0; rr < 4; ++rr) {
        int d = m0 + (wm << 6) + (i << 4) + (quad << 2) + rr;
        if (d < dlen) mx = fmaxf(mx, acc[i][j][rr]);
      }
    float s = 0.f;
#pragma unroll
    for (int i = 0; i < 4; ++i)
#pragma unroll
      for (int rr = 0; rr < 4; ++rr) {
        int d = m0 + (wm << 6) + (i << 4) + (quad << 2) + rr;
        if (d < dlen) s += __expf(acc[i][j][rr] - mx);
      }
#pragma unroll
    for (int off = 16; off < 64; off <<= 1) {
      float om = __shfl_xor(mx, off);
      float os = __shfl_xor(s, off);
      omerge(mx, s, om, os);
    }
    if (quad == 0) {
      int cl = (wn << 6) + (j << 4) + l15;
      cdM[(cl << 1) + wm] = mx;
      cdS[(cl << 1) + wm] = s;
    }
  }
  __syncthreads();
  if (threadIdx.x < 128) {
    int rl = threadIdx.x;
    float m1 = redM[rl << 1], s1 = redS[rl << 1];
    omerge(m1, s1, redM[(rl << 1) + 1], redS[(rl << 1) + 1]);
    int gr = b * LD_ + m0 + rl;
    rowPM[tn * (B_ * LD_) + gr] = m1;
    rowPS[tn * (B_ * LD_) + gr] = s1;
  } else {
    int cl = threadIdx.x - 128;
    float m1 = cdM[cl << 1], s1 = cdS[cl << 1];
    omerge(m1, s1, cdM[(cl << 1) + 1], cdS[(cl << 1) + 1]);
    int gc = b * LQ_ + n0 + cl;
    colPM[tm * (B_ * LQ_) + gc] = m1;
    colPS[tm * (B_ * LQ_) + gc] = s1;
  }
}

// --------- normalize (fused merge): A_d row-major, A_q via LDS transpose, f4 IO
__global__ __launch_bounds__(256) void k_normalize(
    const float* __restrict__ S,
    const float* __restrict__ rowPM, const float* __restrict__ rowPS,
    const float* __restrict__ colPM, const float* __restrict__ colPS,
    const int* __restrict__ qlens, const int* __restrict__ dlens,
    _Float16* __restrict__ Ad, _Float16* __restrict__ Aq) {
  int blk = blockIdx.x;
  int b = blk >> 7, rest = blk & 127, dt = rest >> 3, qt = rest & 7;
  int d0 = dt << 6, q0 = qt << 6;
  int t = threadIdx.x;
  __shared__ float sRM[64], sRI[64], sCM[64], sCI[64];
  __shared__ _Float16 T[64 * 66];
  // merge partial stats for this tile's 64 rows / 64 cols
  if (t < 64) {
    int gr = (b << 10) + d0 + t;
    float m = -1e30f, s = 0.f;
#pragma unroll
    for (int c = 0; c < 4; ++c) omerge(m, s, rowPM[c * (B_ * LD_) + gr], rowPS[c * (B_ * LD_) + gr]);
    sRM[t] = m; sRI[t] = 1.0f / s;
  } else if (t < 128) {
    int u = t - 64;
    int gc = (b << 9) + q0 + u;
    float m = -1e30f, s = 0.f;
#pragma unroll
    for (int c = 0; c < 8; ++c) omerge(m, s, colPM[c * (B_ * LQ_) + gc], colPS[c * (B_ * LQ_) + gc]);
    sCM[u] = m; sCI[u] = 1.0f / s;
  }
  __syncthreads();
  int qlen = qlens[b], dlen = dlens[b];
  const float* Sb = S + (size_t)b * LD_ * LQ_;
  int qq = t & 15, dr = t >> 4;
  float cm4[4], ci4[4];
#pragma unroll
  for (int e = 0; e < 4; ++e) { cm4[e] = sCM[(qq << 2) + e]; ci4[e] = sCI[(qq << 2) + e]; }
#pragma unroll
  for (int it = 0; it < 4; ++it) {
    int dl_ = (it << 4) + dr, d = d0 + dl_;
    float4 s4 = *(const float4*)(Sb + (size_t)d * LQ_ + q0 + (qq << 2));
    float rm = sRM[dl_], ri = sRI[dl_];
    const float* sv = (const float*)&s4;
    bool dvalid = d < dlen;
    half4v adv;
#pragma unroll
    for (int e = 0; e < 4; ++e) {
      int q = q0 + (qq << 2) + e;
      float ad = (q < qlen) ? __expf(sv[e] - rm) * ri : 0.f;
      adv[e] = (_Float16)ad;
      float aq = dvalid ? __expf(sv[e] - cm4[e]) * ci4[e] : 0.f;
      T[((qq << 2) + e) * 66 + dl_] = (_Float16)aq;
    }
    *(half4v*)(Ad + (size_t)b * LD_ * LQ_ + (size_t)d * LQ_ + q0 + (qq << 2)) = adv;
  }
  __syncthreads();
  int c4 = (t & 15) << 2, rq0 = t >> 4;
#pragma unroll
  for (int it = 0; it < 4; ++it) {
    int row = (it << 4) + rq0;
    half4v v;
#pragma unroll
    for (int e = 0; e < 4; ++e) v[e] = T[row * 66 + c4 + e];
    *(half4v*)(Aq + (size_t)b * LQ_ * LD_ + (size_t)(q0 + row) * LD_ + d0 + c4) = v;
  }
}

// -------- C_q: m=q, n=h, k=d. A=Aq[LQ,LD], B=DhT[H,LD]. Writes qout fp32 + QT f16
__global__ __launch_bounds__(256) void k_gemm_cq(const _Float16* __restrict__ Aq,
                                                 const _Float16* __restrict__ DhT,
                                                 _Float16* __restrict__ QT,
                                                 float* __restrict__ out) {
  int raw = blockIdx.x;                       // 512
  int xcd = raw & 7, idx = raw >> 3;
  int b = xcd + ((idx >> 5) << 3);
  int t = idx & 31, tm = t >> 3, tn = t & 7;  // 4 m-tiles (q), 8 n-tiles (h)
  const int K = LD_;
  const _Float16* A = Aq + (size_t)b * LQ_ * LD_;
  const _Float16* Bm = DhT + (size_t)b * H_ * LD_;
  __shared__ _Float16 smem[64 * 136];         // sA(4096) + sB(4096); also 64x136 transpose buf
  _Float16* sA = smem;
  _Float16* sB = smem + 128 * 32;
  int lane = threadIdx.x & 63, wave = threadIdx.x >> 6;
  int wm = wave >> 1, wn = wave & 1;
  int m0 = tm << 7, n0 = tn << 7;
  int srow = lane >> 2, scol = (lane & 3) << 3;

  floatx4 acc[4][4];
  floatx4 z = {0.f, 0.f, 0.f, 0.f};
#pragma unroll
  for (int i = 0; i < 4; ++i)
#pragma unroll
    for (int j = 0; j < 4; ++j) acc[i][j] = z;

  for (int k0 = 0; k0 < K; k0 += 32) {
#pragma unroll
    for (int ts = 0; ts < 2; ++ts) {
      int row = (wave << 5) + (ts << 4) + srow;
      int lo = ((wave << 5) + (ts << 4)) << 5;
      gll16(A + (size_t)(m0 + row) * K + k0 + scol, sA + lo);
      gll16(Bm + (size_t)(n0 + row) * K + k0 + scol, sB + lo);
    }
    __syncthreads();
    int lk = (lane >> 4) << 3, lr = lane & 15;
    half8 af[4], bf[4];
#pragma unroll
    for (int i = 0; i < 4; ++i) {
      af[i] = *(const half8*)(sA + (((wm << 6) + (i << 4) + lr) << 5) + lk);
      bf[i] = *(const half8*)(sB + (((wn << 6) + (i << 4) + lr) << 5) + lk);
    }
#pragma unroll
    for (int i = 0; i < 4; ++i)
#pragma unroll
      for (int j = 0; j < 4; ++j)
        acc[i][j] = __builtin_amdgcn_mfma_f32_16x16x32_f16(af[i], bf[j], acc[i][j], 0, 0, 0);
    __syncthreads();
  }
  float* qoutb = out + OUT1_F + (size_t)b * LQ_ * 2048;
  _Float16* qtb = QT + (size_t)b * 2048 * LQ_;
  int quad = lane >> 4, l15 = lane & 15;
#pragma unroll
  for (int i = 0; i < 4; ++i) {
    int q = m0 + (wm << 6) + (i << 4) + (quad << 2);
#pragma unroll
    for (int j = 0; j < 4; ++j) {
      int h = n0 + (wn << 6) + (j << 4) + l15;
#pragma unroll
      for (int rr = 0; rr < 4; ++rr)
        qoutb[(size_t)(q + rr) * 2048 + 1024 + h] = acc[i][j][rr];  // coalesced over h
    }
  }
  // QT f16 via LDS transpose: pass p handles h-halves (wn==p writes), coalesced 16B stores
  _Float16* sT = smem;  // 64 x 136 (16B-aligned row stride)
#pragma unroll 1
  for (int p = 0; p < 2; ++p) {
    __syncthreads();
    if (wn == p) {
#pragma unroll
      for (int i = 0; i < 4; ++i) {
        int ql_ = (wm << 6) + (i << 4) + (quad << 2);
#pragma unroll
        for (int j = 0; j < 4; ++j) {
          int hl = (j << 4) + l15;
#pragma unroll
          for (int rr = 0; rr < 4; ++rr)
            sT[hl * 136 + ql_ + rr] = (_Float16)acc[i][j][rr];
        }
      }
    }
    __syncthreads();
    int row = threadIdx.x >> 2, ch = (threadIdx.x & 3) << 5;
    _Float16* dst = qtb + (size_t)(1024 + n0 + (p << 6) + row) * LQ_ + m0 + ch;
    const _Float16* srcp = sT + row * 136 + ch;
#pragma unroll
    for (int k = 0; k < 4; ++k)
      *(half8*)(dst + (k << 3)) = *(const half8*)(srcp + (k << 3));
  }
}

// ---------------- C_D = Ad x QoutT: doc_output[:, :, 0:2H] + fused last gather
__global__ __launch_bounds__(256) void k_gemm_cd(const _Float16* __restrict__ Ad,
                                                 const _Float16* __restrict__ QT,
                                                 const int* __restrict__ dlens,
                                                 float* __restrict__ out) {
  int raw = blockIdx.x;                       // 2048
  int xcd = raw & 7, idx = raw >> 3;          // idx 0..255
  int b = xcd + ((idx >> 7) << 3);
  int tile = idx & 127, tm = tile >> 4, tn = tile & 15;
  const int K = LQ_;
  const _Float16* A = Ad + (size_t)b * LD_ * LQ_;
  const _Float16* Bm = QT + (size_t)b * 2048 * LQ_;
  __shared__ _Float16 sA[128 * 32], sB[128 * 32];
  int lane = threadIdx.x & 63, wave = threadIdx.x >> 6;
  int wm = wave >> 1, wn = wave & 1;
  int m0 = tm << 7, n0 = tn << 7;
  int srow = lane >> 2, scol = (lane & 3) << 3;

  floatx4 acc[4][4];
  floatx4 z = {0.f, 0.f, 0.f, 0.f};
#pragma unroll
  for (int i = 0; i < 4; ++i)
#pragma unroll
    for (int j = 0; j < 4; ++j) acc[i][j] = z;

  for (int k0 = 0; k0 < K; k0 += 32) {
#pragma unroll
    for (int ts = 0; ts < 2; ++ts) {
      int row = (wave << 5) + (ts << 4) + srow;
      int lo = ((wave << 5) + (ts << 4)) << 5;
      gll16(A + (size_t)(m0 + row) * K + k0 + scol, sA + lo);
      gll16(Bm + (size_t)(n0 + row) * K + k0 + scol, sB + lo);
    }
    __syncthreads();
    int lk = (lane >> 4) << 3, lr = lane & 15;
    half8 af[4], bf[4];
#pragma unroll
    for (int i = 0; i < 4; ++i) {
      af[i] = *(const half8*)(sA + (((wm << 6) + (i << 4) + lr) << 5) + lk);
      bf[i] = *(const half8*)(sB + (((wn << 6) + (i << 4) + lr) << 5) + lk);
    }
#pragma unroll
    for (int i = 0; i < 4; ++i)
#pragma unroll
      for (int j = 0; j < 4; ++j)
        acc[i][j] = __builtin_amdgcn_mfma_f32_16x16x32_f16(af[i], bf[j], acc[i][j], 0, 0, 0);
    __syncthreads();
  }
  float* db = out + OUT0_F + (size_t)b * LD_ * 3072;
  int dlast = dlens[b] - 1;
  int quad = lane >> 4, l15 = lane & 15;
#pragma unroll
  for (int i = 0; i < 4; ++i) {
    int mb = m0 + (wm << 6) + (i << 4) + (quad << 2);
#pragma unroll
    for (int j = 0; j < 4; ++j) {
      int n = n0 + (wn << 6) + (j << 4) + l15;
#pragma unroll
      for (int rr = 0; rr < 4; ++rr) {
        db[(size_t)(mb + rr) * 3072 + n] = acc[i][j][rr];
        if (mb + rr == dlast) out[OUT2_F + (size_t)b * 3072 + n] = acc[i][j][rr];
      }
    }
  }
}

// ------------------------------------------------------------------- launcher
extern "C" void kernel_launch(void* const* d_in, const int* in_sizes, int n_in,
                              void* d_out, int out_size, void* d_ws, size_t ws_size,
                              hipStream_t stream) {
  const float* Dp = (const float*)d_in[0];
  const float* Qp = (const float*)d_in[1];
  const unsigned char* qmask = (const unsigned char*)d_in[3];
  const int* dlens = (const int*)d_in[4];
  float* out = (float*)d_out;
  char* ws = (char*)d_ws;

  _Float16* Dh  = (_Float16*)(ws + OFF_DH);
  _Float16* Dl  = (_Float16*)(ws + OFF_DL);
  _Float16* Qh  = (_Float16*)(ws + OFF_QH);
  _Float16* Ql  = (_Float16*)(ws + OFF_QL);
  float*    S   = (float*)(ws + OFF_S);
  _Float16* Ad  = (_Float16*)(ws + OFF_AD);
  _Float16* Aq  = (_Float16*)(ws + OFF_AQ);
  _Float16* DhT = (_Float16*)(ws + OFF_DHT);
  _Float16* QT  = (_Float16*)(ws + OFF_QT);
  int*      ql  = (int*)(ws + OFF_QLEN);
  float*    rpm = (float*)(ws + OFF_RPM);
  float*    rps = (float*)(ws + OFF_RPS);
  float*    cpm = (float*)(ws + OFF_CPM);
  float*    cps = (float*)(ws + OFF_CPS);

  k_cast<<<6145, 256, 0, stream>>>(Dp, Qp, dlens, qmask, ql, Dh, Dl, Qh, Ql, DhT, QT, out);
  k_gemm_scores<<<512, 256, 0, stream>>>(Dh, Dl, Qh, Ql, S, ql, dlens, rpm, rps, cpm, cps);
  k_normalize<<<2048, 256, 0, stream>>>(S, rpm, rps, cpm, cps, ql, dlens, Ad, Aq);
  k_gemm_cq<<<512, 256, 0, stream>>>(Aq, DhT, QT, out);
  k_gemm_cd<<<2048, 256, 0, stream>>>(Ad, QT, dlens, out);
}

// Round 3
// 563.497 us; speedup vs baseline: 1.0386x; 1.0143x over previous
//
#include <hip/hip_runtime.h>

#define B_   16
#define LD_  1024
#define LQ_  512
#define H_   1024

// Output section offsets (floats)
#define OUT0_F 0ull                  // doc_output  [B, LD, 3H]
#define OUT1_F 50331648ull           // query_output[B, LQ, 2H]
#define OUT2_F 67108864ull           // last        [B, 3H]

// Workspace layout (bytes) — ws is ~1 GiB, no aliasing needed
#define OFF_DH   0ull               // Dh  [B,LD,H] f16  32MB
#define OFF_DL   33554432ull        // Dl  32MB
#define OFF_QH   67108864ull        // Qh  16MB
#define OFF_QL   83886080ull        // Ql  16MB
#define OFF_S    100663296ull       // S fp32 [B,LD,LQ] 32MB
#define OFF_AD   134217728ull       // A_d f16 [B,LD,LQ] 16MB
#define OFF_AQ   150994944ull       // A_q f16 [B,LQ,LD] 16MB
#define OFF_DHT  167772160ull       // DhT [B,H,LD] f16 32MB
#define OFF_QT   201326592ull       // QoutT [B,2H,LQ] f16 32MB
#define OFF_QLEN 235077632ull
#define OFF_RPM  235077888ull       // row partial max [4][B*LD]
#define OFF_RPS  235340032ull
#define OFF_CPM  235602176ull       // col partial max [8][B*LQ]
#define OFF_CPS  235864320ull

typedef _Float16 half8 __attribute__((ext_vector_type(8)));
typedef _Float16 half4v __attribute__((ext_vector_type(4)));
typedef float floatx4 __attribute__((ext_vector_type(4)));

// ---------------------------------------------------------------- async g->lds
__device__ __forceinline__ void gll16(const _Float16* g, _Float16* l) {
#if __has_builtin(__builtin_amdgcn_global_load_lds)
  __builtin_amdgcn_global_load_lds(
      (const __attribute__((address_space(1))) unsigned int*)(unsigned long long)g,
      (__attribute__((address_space(3))) unsigned int*)(unsigned int)(unsigned long long)l,
      16, 0, 0);
#else
  int lane = threadIdx.x & 63;
  *(half8*)(l + lane * 8) = *(const half8*)(g + lane * 8);
#endif
}

__device__ __forceinline__ void omerge(float& m, float& s, float pm, float ps) {
  float nm = fmaxf(m, pm);
  s = s * __expf(m - nm) + ps * __expf(pm - nm);
  m = nm;
}

// -------- cast/split + fp32 passthru copies + fused f16 transposes + qlens blk
__global__ __launch_bounds__(256) void k_cast(
    const float* __restrict__ Dp, const float* __restrict__ Qp,
    const int* __restrict__ dlens,
    const unsigned char* __restrict__ qm, int* __restrict__ qlens,
    _Float16* __restrict__ Dh, _Float16* __restrict__ Dl,
    _Float16* __restrict__ Qh, _Float16* __restrict__ Ql,
    _Float16* __restrict__ DhT, _Float16* __restrict__ QT,
    float* __restrict__ out) {
  int bid = blockIdx.x;
  if (bid == 6144) {
    // ---- q_lens from mask buf (one light block, hidden under the cast grid)
    __shared__ unsigned or_hi, is_f32;
    __shared__ int scnt[B_];
    if (threadIdx.x == 0) { or_hi = 0u; is_f32 = 0u; }
    if (threadIdx.x < B_) scnt[threadIdx.x] = 0;
    __syncthreads();
    const unsigned* w = (const unsigned*)qm;
    unsigned lo = 0u, lf = 0u;
    for (int i = threadIdx.x; i < (B_ * LQ_) / 4; i += 256) {
      unsigned v = w[i];
      lo |= (v >> 8);
      if (v == 0x3F800000u) lf = 1u;
    }
    if (lo) atomicOr(&or_hi, 1u);
    if (lf) atomicOr(&is_f32, 1u);
    __syncthreads();
    int esize4 = (or_hi == 0u) || is_f32;  // i32/f32 storage
    for (int idx = threadIdx.x; idx < B_ * LQ_; idx += 256) {
      int b = idx >> 9;
      int z;
      if (esize4) z = (((const unsigned*)qm)[idx] == 0u);
      else        z = (qm[idx] == 0);
      if (z) atomicAdd(&scnt[b], 1);
    }
    __syncthreads();
    if (threadIdx.x < B_) qlens[threadIdx.x] = scnt[threadIdx.x];
    return;
  }
  __shared__ _Float16 T[64 * 66];
  int t = threadIdx.x;
  int r = t >> 2, cb = (t & 3) << 4;
  bool isD = bid < 4096;
  int b, r0, c0;
  const float* src;
  if (isD) {   // D: [LD,H] 16x16 tiles of 64x64 per batch
    b = bid >> 8; int rest = bid & 255; r0 = (rest >> 4) << 6; c0 = (rest & 15) << 6;
    src = Dp + (size_t)b * LD_ * H_;
  } else {     // Q: [LQ,H] 8x16 tiles per batch
    int t2 = bid - 4096;
    b = t2 >> 7; int rest = t2 & 127; r0 = (rest >> 4) << 6; c0 = (rest & 15) << 6;
    src = Qp + (size_t)b * LQ_ * H_;
  }
  size_t eoff = (size_t)(r0 + r) * H_ + c0 + cb;
  float4 v[4];
#pragma unroll
  for (int k = 0; k < 4; ++k) v[k] = *(const float4*)(src + eoff + (k << 2));
  half4v hi4[4], lo4[4];
#pragma unroll
  for (int k = 0; k < 4; ++k) {
    const float* f = (const float*)&v[k];
#pragma unroll
    for (int e = 0; e < 4; ++e) {
      _Float16 h = (_Float16)f[e];
      hi4[k][e] = h;
      lo4[k][e] = (_Float16)(f[e] - (float)h);
    }
  }
  if (isD) {
    _Float16* dh = Dh + (size_t)b * LD_ * H_ + eoff;
    _Float16* dl = Dl + (size_t)b * LD_ * H_ + eoff;
    float* dob = out + OUT0_F + (size_t)b * LD_ * 3072 + (size_t)(r0 + r) * 3072 + 2048 + c0 + cb;
#pragma unroll
    for (int k = 0; k < 4; ++k) {
      *(half4v*)(dh + (k << 2)) = hi4[k];
      *(half4v*)(dl + (k << 2)) = lo4[k];
      *(float4*)(dob + (k << 2)) = v[k];
    }
    if (r0 + r == dlens[b] - 1) {
      float* o2 = out + OUT2_F + (size_t)b * 3072 + 2048 + c0 + cb;
#pragma unroll
      for (int k = 0; k < 4; ++k) *(float4*)(o2 + (k << 2)) = v[k];
    }
  } else {
    _Float16* qh = Qh + (size_t)b * LQ_ * H_ + eoff;
    _Float16* ql = Ql + (size_t)b * LQ_ * H_ + eoff;
    float* qob = out + OUT1_F + (size_t)b * LQ_ * 2048 + (size_t)(r0 + r) * 2048 + c0 + cb;
#pragma unroll
    for (int k = 0; k < 4; ++k) {
      *(half4v*)(qh + (k << 2)) = hi4[k];
      *(half4v*)(ql + (k << 2)) = lo4[k];
      *(float4*)(qob + (k << 2)) = v[k];
    }
  }
  // LDS transpose of hi
#pragma unroll
  for (int k = 0; k < 4; ++k)
#pragma unroll
    for (int e = 0; e < 4; ++e)
      T[r * 66 + cb + (k << 2) + e] = hi4[k][e];
  __syncthreads();
  int ho = t >> 2, wb = (t & 3) << 4;
  half4v o[4];
#pragma unroll
  for (int k = 0; k < 4; ++k)
#pragma unroll
    for (int e = 0; e < 4; ++e)
      o[k][e] = T[(wb + (k << 2) + e) * 66 + ho];
  half8 h8a, h8b;
#pragma unroll
  for (int e = 0; e < 4; ++e) {
    h8a[e] = o[0][e]; h8a[e + 4] = o[1][e];
    h8b[e] = o[2][e]; h8b[e + 4] = o[3][e];
  }
  if (isD) {
    _Float16* dt = DhT + (size_t)b * H_ * LD_ + (size_t)(c0 + ho) * LD_ + r0 + wb;
    *(half8*)(dt) = h8a;
    *(half8*)(dt + 8) = h8b;
  } else {
    _Float16* qt = QT + (size_t)b * 2048 * LQ_ + (size_t)(c0 + ho) * LQ_ + r0 + wb;
    *(half8*)(qt) = h8a;
    *(half8*)(qt + 8) = h8b;
  }
}

// ---------------- scores: S = Dh Qh^T + cross terms, fused partial softmax stats
// 512 threads / 8 waves (4m x 2n), per-wave 32x64 output, 2 blocks/CU target.
__global__ __launch_bounds__(512, 4) void k_gemm_scores(
    const _Float16* __restrict__ Dh, const _Float16* __restrict__ Dl,
    const _Float16* __restrict__ Qh, const _Float16* __restrict__ Ql,
    float* __restrict__ S, const int* __restrict__ qlens, const int* __restrict__ dlens,
    float* __restrict__ rowPM, float* __restrict__ rowPS,
    float* __restrict__ colPM, float* __restrict__ colPS) {
  int raw = blockIdx.x;                       // 512 blocks; XCD-swizzle: batch per XCD
  int xcd = raw & 7, idx = raw >> 3;          // idx 0..63
  int b = xcd + ((idx >> 5) << 3);            // 2 batches per XCD
  int t = idx & 31, tm = t >> 2, tn = t & 3;  // 8 m-tiles, 4 n-tiles
  const int K = H_;
  const _Float16* Ah = Dh + (size_t)b * LD_ * H_;
  const _Float16* Al = Dl + (size_t)b * LD_ * H_;
  const _Float16* Bh = Qh + (size_t)b * LQ_ * H_;
  const _Float16* Bl = Ql + (size_t)b * LQ_ * H_;
  float* Cb = S + (size_t)b * LD_ * LQ_;

  __shared__ _Float16 sAh[128 * 32], sAl[128 * 32], sBh[128 * 32], sBl[128 * 32];
  int lane = threadIdx.x & 63, wave = threadIdx.x >> 6;  // 8 waves
  int wm = wave >> 1, wn = wave & 1;                     // 4m x 2n
  int m0 = tm << 7, n0 = tn << 7;
  int srow = lane >> 2, scol = (lane & 3) << 3;

  floatx4 acc[2][4];
  floatx4 z = {0.f, 0.f, 0.f, 0.f};
#pragma unroll
  for (int i = 0; i < 2; ++i)
#pragma unroll
    for (int j = 0; j < 4; ++j) acc[i][j] = z;

  for (int k0 = 0; k0 < K; k0 += 32) {
    // each wave stages 16 rows of each stream
    {
      int row = (wave << 4) + srow;
      int lo = (wave << 4) << 5;
      size_t ga = (size_t)(m0 + row) * K + k0 + scol;
      size_t gb = (size_t)(n0 + row) * K + k0 + scol;
      gll16(Ah + ga, sAh + lo);
      gll16(Al + ga, sAl + lo);
      gll16(Bh + gb, sBh + lo);
      gll16(Bl + gb, sBl + lo);
    }
    __syncthreads();
    int lk = (lane >> 4) << 3, lr = lane & 15;
    half8 ah[2], al4[2], bh[4], bl4[4];
#pragma unroll
    for (int i = 0; i < 2; ++i) {
      int ar = ((wm << 5) + (i << 4) + lr) << 5;
      ah[i]  = *(const half8*)(sAh + ar + lk);
      al4[i] = *(const half8*)(sAl + ar + lk);
    }
#pragma unroll
    for (int j = 0; j < 4; ++j) {
      int br = ((wn << 6) + (j << 4) + lr) << 5;
      bh[j]  = *(const half8*)(sBh + br + lk);
      bl4[j] = *(const half8*)(sBl + br + lk);
    }
#pragma unroll
    for (int i = 0; i < 2; ++i)
#pragma unroll
      for (int j = 0; j < 4; ++j) {
        acc[i][j] = __builtin_amdgcn_mfma_f32_16x16x32_f16(ah[i],  bh[j],  acc[i][j], 0, 0, 0);
        acc[i][j] = __builtin_amdgcn_mfma_f32_16x16x32_f16(ah[i],  bl4[j], acc[i][j], 0, 0, 0);
        acc[i][j] = __builtin_amdgcn_mfma_f32_16x16x32_f16(al4[i], bh[j],  acc[i][j], 0, 0, 0);
      }
    __syncthreads();
  }
  int quad = lane >> 4, l15 = lane & 15;
  // store S
#pragma unroll
  for (int i = 0; i < 2; ++i) {
    int mb = m0 + (wm << 5) + (i << 4) + (quad << 2);
#pragma unroll
    for (int j = 0; j < 4; ++j) {
      int n = n0 + (wn << 6) + (j << 4) + l15;
#pragma unroll
      for (int rr = 0; rr < 4; ++rr)
        Cb[(size_t)(mb + rr) * LQ_ + n] = acc[i][j][rr];
    }
  }
  // ---- fused partial softmax stats (reuse LDS) ----
  int qlen = qlens[b], dlen = dlens[b];
  float* redM = (float*)sAh;  // [128][2]
  float* redS = (float*)sAl;
  float* cdM  = (float*)sBh;  // [128][4]
  float* cdS  = (float*)sBl;
  // row partials: per row, over this block's 128 cols (q < qlen mask)
#pragma unroll
  for (int i = 0; i < 2; ++i) {
#pragma unroll
    for (int rr = 0; rr < 4; ++rr) {
      float mx = -1e30f;
#pragma unroll
      for (int j = 0; j < 4; ++j) {
        int q = n0 + (wn << 6) + (j << 4) + l15;
        if (q < qlen) mx = fmaxf(mx, acc[i][j][rr]);
      }
      float s = 0.f;
#pragma unroll
      for (int j = 0; j < 4; ++j) {
        int q = n0 + (wn << 6) + (j << 4) + l15;
        if (q < qlen) s += __expf(acc[i][j][rr] - mx);
      }
#pragma unroll
      for (int off = 1; off < 16; off <<= 1) {
        float om = __shfl_xor(mx, off);
        float os = __shfl_xor(s, off);
        omerge(mx, s, om, os);
      }
      if (l15 == 0) {
        int rl = (wm << 5) + (i << 4) + (quad << 2) + rr;
        redM[(rl << 1) + wn] = mx;
        redS[(rl << 1) + wn] = s;
      }
    }
  }
  // col partials: per col, over this wave's 32 rows (d < dlen mask); 4 wm parts
#pragma unroll
  for (int j = 0; j < 4; ++j) {
    float mx = -1e30f;
#pragma unroll
    for (int i = 0; i < 2; ++i)
#pragma unroll
      for (int rr = 0; rr < 4; ++rr) {
        int d = m0 + (wm << 5) + (i << 4) + (quad << 2) + rr;
        if (d < dlen) mx = fmaxf(mx, acc[i][j][rr]);
      }
    float s = 0.f;
#pragma unroll
    for (int i = 0; i < 2; ++i)
#pragma unroll
      for (int rr = 0; rr < 4; ++rr) {
        int d = m0 + (wm << 5) + (i << 4) + (quad << 2) + rr;
        if (d < dlen) s += __expf(acc[i][j][rr] - mx);
      }
#pragma unroll
    for (int off = 16; off < 64; off <<= 1) {
      float om = __shfl_xor(mx, off);
      float os = __shfl_xor(s, off);
      omerge(mx, s, om, os);
    }
    if (quad == 0) {
      int cl = (wn << 6) + (j << 4) + l15;
      cdM[(cl << 2) + wm] = mx;
      cdS[(cl << 2) + wm] = s;
    }
  }
  __syncthreads();
  if (threadIdx.x < 128) {
    int rl = threadIdx.x;
    float m1 = redM[rl << 1], s1 = redS[rl << 1];
    omerge(m1, s1, redM[(rl << 1) + 1], redS[(rl << 1) + 1]);
    int gr = b * LD_ + m0 + rl;
    rowPM[tn * (B_ * LD_) + gr] = m1;
    rowPS[tn * (B_ * LD_) + gr] = s1;
  } else if (threadIdx.x < 256) {
    int cl = threadIdx.x - 128;
    float m1 = -1e30f, s1 = 0.f;
#pragma unroll
    for (int c = 0; c < 4; ++c) omerge(m1, s1, cdM[(cl << 2) + c], cdS[(cl << 2) + c]);
    int gc = b * LQ_ + n0 + cl;
    colPM[tm * (B_ * LQ_) + gc] = m1;
    colPS[tm * (B_ * LQ_) + gc] = s1;
  }
}

// --------- normalize (fused merge): A_d row-major, A_q via LDS transpose, f4 IO
__global__ __launch_bounds__(256) void k_normalize(
    const float* __restrict__ S,
    const float* __restrict__ rowPM, const float* __restrict__ rowPS,
    const float* __restrict__ colPM, const float* __restrict__ colPS,
    const int* __restrict__ qlens, const int* __restrict__ dlens,
    _Float16* __restrict__ Ad, _Float16* __restrict__ Aq) {
  int blk = blockIdx.x;
  int b = blk >> 7, rest = blk & 127, dt = rest >> 3, qt = rest & 7;
  int d0 = dt << 6, q0 = qt << 6;
  int t = threadIdx.x;
  __shared__ float sRM[64], sRI[64], sCM[64], sCI[64];
  __shared__ _Float16 T[64 * 66];
  // merge partial stats for this tile's 64 rows / 64 cols
  if (t < 64) {
    int gr = (b << 10) + d0 + t;
    float m = -1e30f, s = 0.f;
#pragma unroll
    for (int c = 0; c < 4; ++c) omerge(m, s, rowPM[c * (B_ * LD_) + gr], rowPS[c * (B_ * LD_) + gr]);
    sRM[t] = m; sRI[t] = 1.0f / s;
  } else if (t < 128) {
    int u = t - 64;
    int gc = (b << 9) + q0 + u;
    float m = -1e30f, s = 0.f;
#pragma unroll
    for (int c = 0; c < 8; ++c) omerge(m, s, colPM[c * (B_ * LQ_) + gc], colPS[c * (B_ * LQ_) + gc]);
    sCM[u] = m; sCI[u] = 1.0f / s;
  }
  __syncthreads();
  int qlen = qlens[b], dlen = dlens[b];
  const float* Sb = S + (size_t)b * LD_ * LQ_;
  int qq = t & 15, dr = t >> 4;
  float cm4[4], ci4[4];
#pragma unroll
  for (int e = 0; e < 4; ++e) { cm4[e] = sCM[(qq << 2) + e]; ci4[e] = sCI[(qq << 2) + e]; }
#pragma unroll
  for (int it = 0; it < 4; ++it) {
    int dl_ = (it << 4) + dr, d = d0 + dl_;
    float4 s4 = *(const float4*)(Sb + (size_t)d * LQ_ + q0 + (qq << 2));
    float rm = sRM[dl_], ri = sRI[dl_];
    const float* sv = (const float*)&s4;
    bool dvalid = d < dlen;
    half4v adv;
#pragma unroll
    for (int e = 0; e < 4; ++e) {
      int q = q0 + (qq << 2) + e;
      float ad = (q < qlen) ? __expf(sv[e] - rm) * ri : 0.f;
      adv[e] = (_Float16)ad;
      float aq = dvalid ? __expf(sv[e] - cm4[e]) * ci4[e] : 0.f;
      T[((qq << 2) + e) * 66 + dl_] = (_Float16)aq;
    }
    *(half4v*)(Ad + (size_t)b * LD_ * LQ_ + (size_t)d * LQ_ + q0 + (qq << 2)) = adv;
  }
  __syncthreads();
  int c4 = (t & 15) << 2, rq0 = t >> 4;
#pragma unroll
  for (int it = 0; it < 4; ++it) {
    int row = (it << 4) + rq0;
    half4v v;
#pragma unroll
    for (int e = 0; e < 4; ++e) v[e] = T[row * 66 + c4 + e];
    *(half4v*)(Aq + (size_t)b * LQ_ * LD_ + (size_t)(q0 + row) * LD_ + d0 + c4) = v;
  }
}

// -------- C_q: m=q, n=h, k=d. A=Aq[LQ,LD], B=DhT[H,LD]. Writes qout fp32 + QT f16
// 512 threads / 8 waves (4m x 2n), per-wave 32x64 output.
__global__ __launch_bounds__(512, 4) void k_gemm_cq(const _Float16* __restrict__ Aq,
                                                 const _Float16* __restrict__ DhT,
                                                 _Float16* __restrict__ QT,
                                                 float* __restrict__ out) {
  int raw = blockIdx.x;                       // 512
  int xcd = raw & 7, idx = raw >> 3;
  int b = xcd + ((idx >> 5) << 3);
  int t = idx & 31, tm = t >> 3, tn = t & 7;  // 4 m-tiles (q), 8 n-tiles (h)
  const int K = LD_;
  const _Float16* A = Aq + (size_t)b * LQ_ * LD_;
  const _Float16* Bm = DhT + (size_t)b * H_ * LD_;
  __shared__ _Float16 smem[64 * 136];         // sA(4096) + sB(4096); also 64x136 transpose buf
  _Float16* sA = smem;
  _Float16* sB = smem + 128 * 32;
  int lane = threadIdx.x & 63, wave = threadIdx.x >> 6;  // 8 waves
  int wm = wave >> 1, wn = wave & 1;                     // 4m x 2n
  int m0 = tm << 7, n0 = tn << 7;
  int srow = lane >> 2, scol = (lane & 3) << 3;

  floatx4 acc[2][4];
  floatx4 z = {0.f, 0.f, 0.f, 0.f};
#pragma unroll
  for (int i = 0; i < 2; ++i)
#pragma unroll
    for (int j = 0; j < 4; ++j) acc[i][j] = z;

  for (int k0 = 0; k0 < K; k0 += 32) {
    {
      int row = (wave << 4) + srow;
      int lo = (wave << 4) << 5;
      gll16(A + (size_t)(m0 + row) * K + k0 + scol, sA + lo);
      gll16(Bm + (size_t)(n0 + row) * K + k0 + scol, sB + lo);
    }
    __syncthreads();
    int lk = (lane >> 4) << 3, lr = lane & 15;
    half8 af[2], bf[4];
#pragma unroll
    for (int i = 0; i < 2; ++i)
      af[i] = *(const half8*)(sA + (((wm << 5) + (i << 4) + lr) << 5) + lk);
#pragma unroll
    for (int j = 0; j < 4; ++j)
      bf[j] = *(const half8*)(sB + (((wn << 6) + (j << 4) + lr) << 5) + lk);
#pragma unroll
    for (int i = 0; i < 2; ++i)
#pragma unroll
      for (int j = 0; j < 4; ++j)
        acc[i][j] = __builtin_amdgcn_mfma_f32_16x16x32_f16(af[i], bf[j], acc[i][j], 0, 0, 0);
    __syncthreads();
  }
  float* qoutb = out + OUT1_F + (size_t)b * LQ_ * 2048;
  _Float16* qtb = QT + (size_t)b * 2048 * LQ_;
  int quad = lane >> 4, l15 = lane & 15;
#pragma unroll
  for (int i = 0; i < 2; ++i) {
    int q = m0 + (wm << 5) + (i << 4) + (quad << 2);
#pragma unroll
    for (int j = 0; j < 4; ++j) {
      int h = n0 + (wn << 6) + (j << 4) + l15;
#pragma unroll
      for (int rr = 0; rr < 4; ++rr)
        qoutb[(size_t)(q + rr) * 2048 + 1024 + h] = acc[i][j][rr];  // coalesced over h
    }
  }
  // QT f16 via LDS transpose: pass p handles h-halves (wn==p writes), coalesced 16B stores
  _Float16* sT = smem;  // 64 x 136 (16B-aligned row stride)
#pragma unroll 1
  for (int p = 0; p < 2; ++p) {
    __syncthreads();
    if (wn == p) {
#pragma unroll
      for (int i = 0; i < 2; ++i) {
        int ql_ = (wm << 5) + (i << 4) + (quad << 2);
#pragma unroll
        for (int j = 0; j < 4; ++j) {
          int hl = (j << 4) + l15;
#pragma unroll
          for (int rr = 0; rr < 4; ++rr)
            sT[hl * 136 + ql_ + rr] = (_Float16)acc[i][j][rr];
        }
      }
    }
    __syncthreads();
    int row = threadIdx.x >> 3, ch = (threadIdx.x & 7) << 4;
    _Float16* dst = qtb + (size_t)(1024 + n0 + (p << 6) + row) * LQ_ + m0 + ch;
    const _Float16* srcp = sT + row * 136 + ch;
    *(half8*)(dst) = *(const half8*)(srcp);
    *(half8*)(dst + 8) = *(const half8*)(srcp + 8);
  }
}

// ---------------- C_D = Ad x QoutT: doc_output[:, :, 0:2H] + fused last gather
__global__ __launch_bounds__(256) void k_gemm_cd(const _Float16* __restrict__ Ad,
                                                 const _Float16* __restrict__ QT,
                                                 const int* __restrict__ dlens,
                                                 float* __restrict__ out) {
  int raw = blockIdx.x;                       // 2048
  int xcd = raw & 7, idx = raw >> 3;          // idx 0..255
  int b = xcd + ((idx >> 7) << 3);
  int tile = idx & 127, tm = tile >> 4, tn = tile & 15;
  const int K = LQ_;
  const _Float16* A = Ad + (size_t)b * LD_ * LQ_;
  const _Float16* Bm = QT + (size_t)b * 2048 * LQ_;
  __shared__ _Float16 sA[128 * 32], sB[128 * 32];
  int lane = threadIdx.x & 63, wave = threadIdx.x >> 6;
  int wm = wave >> 1, wn = wave & 1;
  int m0 = tm << 7, n0 = tn << 7;
  int srow = lane >> 2, scol = (lane & 3) << 3;

  floatx4 acc[4][4];
  floatx4 z = {0.f, 0.f, 0.f, 0.f};
#pragma unroll
  for (int i = 0; i < 4; ++i)
#pragma unroll
    for (int j = 0; j < 4; ++j) acc[i][j] = z;

  for (int k0 = 0; k0 < K; k0 += 32) {
#pragma unroll
    for (int ts = 0; ts < 2; ++ts) {
      int row = (wave << 5) + (ts << 4) + srow;
      int lo = ((wave << 5) + (ts << 4)) << 5;
      gll16(A + (size_t)(m0 + row) * K + k0 + scol, sA + lo);
      gll16(Bm + (size_t)(n0 + row) * K + k0 + scol, sB + lo);
    }
    __syncthreads();
    int lk = (lane >> 4) << 3, lr = lane & 15;
    half8 af[4], bf[4];
#pragma unroll
    for (int i = 0; i < 4; ++i) {
      af[i] = *(const half8*)(sA + (((wm << 6) + (i << 4) + lr) << 5) + lk);
      bf[i] = *(const half8*)(sB + (((wn << 6) + (i << 4) + lr) << 5) + lk);
    }
#pragma unroll
    for (int i = 0; i < 4; ++i)
#pragma unroll
      for (int j = 0; j < 4; ++j)
        acc[i][j] = __builtin_amdgcn_mfma_f32_16x16x32_f16(af[i], bf[j], acc[i][j], 0, 0, 0);
    __syncthreads();
  }
  float* db = out + OUT0_F + (size_t)b * LD_ * 3072;
  int dlast = dlens[b] - 1;
  int quad = lane >> 4, l15 = lane & 15;
#pragma unroll
  for (int i = 0; i < 4; ++i) {
    int mb = m0 + (wm << 6) + (i << 4) + (quad << 2);
#pragma unroll
    for (int j = 0; j < 4; ++j) {
      int n = n0 + (wn << 6) + (j << 4) + l15;
#pragma unroll
      for (int rr = 0; rr < 4; ++rr) {
        db[(size_t)(mb + rr) * 3072 + n] = acc[i][j][rr];
        if (mb + rr == dlast) out[OUT2_F + (size_t)b * 3072 + n] = acc[i][j][rr];
      }
    }
  }
}

// ------------------------------------------------------------------- launcher
extern "C" void kernel_launch(void* const* d_in, const int* in_sizes, int n_in,
                              void* d_out, int out_size, void* d_ws, size_t ws_size,
                              hipStream_t stream) {
  const float* Dp = (const float*)d_in[0];
  const float* Qp = (const float*)d_in[1];
  const unsigned char* qmask = (const unsigned char*)d_in[3];
  const int* dlens = (const int*)d_in[4];
  float* out = (float*)d_out;
  char* ws = (char*)d_ws;

  _Float16* Dh  = (_Float16*)(ws + OFF_DH);
  _Float16* Dl  = (_Float16*)(ws + OFF_DL);
  _Float16* Qh  = (_Float16*)(ws + OFF_QH);
  _Float16* Ql  = (_Float16*)(ws + OFF_QL);
  float*    S   = (float*)(ws + OFF_S);
  _Float16* Ad  = (_Float16*)(ws + OFF_AD);
  _Float16* Aq  = (_Float16*)(ws + OFF_AQ);
  _Float16* DhT = (_Float16*)(ws + OFF_DHT);
  _Float16* QT  = (_Float16*)(ws + OFF_QT);
  int*      ql  = (int*)(ws + OFF_QLEN);
  float*    rpm = (float*)(ws + OFF_RPM);
  float*    rps = (float*)(ws + OFF_RPS);
  float*    cpm = (float*)(ws + OFF_CPM);
  float*    cps = (float*)(ws + OFF_CPS);

  k_cast<<<6145, 256, 0, stream>>>(Dp, Qp, dlens, qmask, ql, Dh, Dl, Qh, Ql, DhT, QT, out);
  k_gemm_scores<<<512, 512, 0, stream>>>(Dh, Dl, Qh, Ql, S, ql, dlens, rpm, rps, cpm, cps);
  k_normalize<<<2048, 256, 0, stream>>>(S, rpm, rps, cpm, cps, ql, dlens, Ad, Aq);
  k_gemm_cq<<<512, 512, 0, stream>>>(Aq, DhT, QT, out);
  k_gemm_cd<<<2048, 256, 0, stream>>>(Ad, QT, dlens, out);
}